// Round 7
// baseline (157.890 us; speedup 1.0000x reference)
//
#include <hip/hip_runtime.h>
#include <math.h>

// Dims (fixed per reference)
#define B   128
#define L   50
#define V   100000
#define ND  4
#define D   64

// out layout: P_v (B*V) | infomax_loss (1) | gnn (B*ND*L*D)

__device__ __forceinline__ float log_sigmoid(float x) {
    if (x >= 0.f) return -log1pf(expf(-x));
    return x - log1pf(expf(x));
}

// K1: per-b block. Gather session_emb, write gnn (4 broadcast copies),
// masked-mean graph_rep + last row (in LDS), then u = W_im@gr and
// h = tanh([gr|last]@W_pvsd + b). Block 0 also zero-inits the loss slot
// (k3 accumulates into it atomically; stream order guarantees k1 < k3).
__global__ __launch_bounds__(256) void k1_fused(
    const int* __restrict__ nodes, const int* __restrict__ mask,
    const int* __restrict__ sli, const float* __restrict__ emb_i,
    const float* __restrict__ W_pvsd, const float* __restrict__ b_pvsd,
    const float* __restrict__ W_im,
    float* __restrict__ gnn_out, float* __restrict__ u, float* __restrict__ h,
    float* __restrict__ loss)
{
    const int b = blockIdx.x;
    const int t = threadIdx.x;
    if (b == 0 && t == 0) loss[0] = 0.f;
    __shared__ int   s_nodes[L];
    __shared__ float s_mask[L];
    __shared__ float s_part[4][D];
    __shared__ float s_gr[D], s_last[D];
    if (t < L) {
        s_nodes[t] = nodes[b * L + t];
        s_mask[t]  = (float)mask[b * L + t];
    }
    __syncthreads();
    const int d  = t & 63;
    const int l0 = t >> 6;
    float acc = 0.f;
    for (int l = l0; l < L; l += 4) {
        float val = emb_i[(size_t)s_nodes[l] * D + d];
        size_t o = ((size_t)(b * ND + 0) * L + l) * D + d;
        gnn_out[o]                   = val;
        gnn_out[o + (size_t)L * D]   = val;
        gnn_out[o + 2*(size_t)L * D] = val;
        gnn_out[o + 3*(size_t)L * D] = val;
        acc += s_mask[l] * val;
    }
    s_part[l0][d] = acc;
    __syncthreads();
    if (t < D) {
        float msum = 0.f;
        for (int l = 0; l < L; ++l) msum += s_mask[l];
        float s = s_part[0][t] + s_part[1][t] + s_part[2][t] + s_part[3][t];
        s_gr[t]   = s / msum;
        s_last[t] = emb_i[(size_t)s_nodes[sli[b]] * D + t];
    }
    __syncthreads();
    if (t < D) {
        float uu = 0.f;
        #pragma unroll
        for (int e = 0; e < D; ++e) uu += W_im[t * D + e] * s_gr[e];
        u[b * D + t] = uu;
        float pre = b_pvsd[t];
        #pragma unroll
        for (int k = 0; k < D; ++k) pre += s_gr[k]   * W_pvsd[k * D + t];
        #pragma unroll
        for (int k = 0; k < D; ++k) pre += s_last[k] * W_pvsd[(D + k) * D + t];
        h[b * D + t] = tanhf(pre);
    }
}

// K3: infomax partials per b, accumulated straight into the scalar loss.
// (128 atomicAdds total; fp reorder drift ~1e-7 << tolerance.)
__global__ __launch_bounds__(64) void k3_infomax(
    const float* __restrict__ u, const float* __restrict__ gnn,
    float* __restrict__ loss)
{
    const int b = blockIdx.x;
    const int t = threadIdx.x;
    __shared__ float s_up[D], s_un[D];
    const int bm1 = (b + B - 1) % B;
    s_up[t] = u[b * D + t];
    s_un[t] = u[bm1 * D + t];
    __syncthreads();
    float lsp = 0.f, lsn = 0.f;
    if (t < L) {
        const float* se = gnn + ((size_t)(b * ND) * L + t) * D;  // n=0 copy
        float sp = 0.f, sn = 0.f;
        #pragma unroll
        for (int d2 = 0; d2 < D; ++d2) {
            float vv = se[d2];
            sp += vv * s_up[d2];
            sn += vv * s_un[d2];
        }
        lsp = log_sigmoid(sp);
        lsn = log_sigmoid(-sn);
    }
    float tot = lsp + lsn;
    for (int off = 32; off > 0; off >>= 1) tot += __shfl_down(tot, off);
    if (t == 0) atomicAdd(loss, -tot / (float)(B * L));
}

// K5: P_v[b,v] = h[b] . emb_i[v]
// R5 post-mortem: the compiler sinks row-resident loads into the b-loop
// no matter the VGPR budget (VGPR stuck at 56, cache-latency bound).
// So invert the nest: acc[NB] persistent (32 VGPRs), STREAM the row —
// each of the 16 row quads is loaded once and applied to all 32 b's.
// Nothing left to sink; 32 independent FMA chains give the ILP.
// h[] reads are wave-uniform -> s_load through the scalar cache.
// 1-D grid: bx=id>>2 (v tile), by=id&3 (b slice) so the 4 slices touching
// the same emb rows are temporally adjacent -> L2/L3 absorb the refetch.
#define NBSPLIT 4
#define NB (B / NBSPLIT)   // 32 b per thread
__global__ __launch_bounds__(256) void k5_pv(
    const float* __restrict__ h, const float* __restrict__ emb_i,
    float* __restrict__ pv)
{
    const int bx = blockIdx.x >> 2;
    const int by = blockIdx.x & 3;
    const int v  = bx * 256 + threadIdx.x;
    const int b0 = by * NB;
    const bool active = (v < V);
    const int vc = active ? v : (V - 1);
    const float4* r4 = reinterpret_cast<const float4*>(emb_i + (size_t)vc * D);
    const float4* h4 = reinterpret_cast<const float4*>(h) + (size_t)b0 * (D / 4);

    float acc[NB];
    #pragma unroll
    for (int j = 0; j < NB; ++j) acc[j] = 0.f;

    for (int K = 0; K < D / 4; ++K) {
        float4 rq = r4[K];
        #pragma unroll
        for (int j = 0; j < NB; ++j) {
            float4 hv = h4[j * (D / 4) + K];   // uniform -> s_load_dwordx4
            acc[j] += rq.x * hv.x;
            acc[j] += rq.y * hv.y;
            acc[j] += rq.z * hv.z;
            acc[j] += rq.w * hv.w;
        }
    }
    if (active) {
        #pragma unroll
        for (int j = 0; j < NB; ++j)
            pv[(size_t)(b0 + j) * V + v] = acc[j];
    }
}

extern "C" void kernel_launch(void* const* d_in, const int* in_sizes, int n_in,
                              void* d_out, int out_size, void* d_ws, size_t ws_size,
                              hipStream_t stream)
{
    const int*   nodes  = (const int*)d_in[0];
    const int*   sli    = (const int*)d_in[4];
    const int*   mask   = (const int*)d_in[6];
    const float* emb_i  = (const float*)d_in[7];
    const float* W_pvsd = (const float*)d_in[13];
    const float* b_pvsd = (const float*)d_in[14];
    const float* W_im   = (const float*)d_in[15];

    float* pv   = (float*)d_out;               // B*V
    float* loss = pv + (size_t)B * V;          // 1
    float* gnn  = loss + 1;                    // B*ND*L*D

    float* ws = (float*)d_ws;
    float* u  = ws;                            // B*D
    float* h  = u + B * D;                     // B*D

    k1_fused<<<B, 256, 0, stream>>>(nodes, mask, sli, emb_i, W_pvsd, b_pvsd,
                                    W_im, gnn, u, h, loss);
    k3_infomax<<<B, 64, 0, stream>>>(u, gnn, loss);
    k5_pv<<<((V + 255) / 256) * NBSPLIT, 256, 0, stream>>>(h, emb_i, pv);
}

// Round 9
// 67.544 us; speedup vs baseline: 2.3376x; 2.3376x over previous
//
#include <hip/hip_runtime.h>
#include <math.h>

// Dims (fixed per reference)
#define B   128
#define L   50
#define V   100000
#define ND  4
#define D   64

// out layout: P_v (B*V) | infomax_loss (1) | gnn (B*ND*L*D)

__device__ __forceinline__ float log_sigmoid(float x) {
    if (x >= 0.f) return -log1pf(expf(-x));
    return x - log1pf(expf(x));
}

// K1: per-b block. Gather session_emb, write gnn (4 broadcast copies),
// masked-mean graph_rep + last row (in LDS), then u = W_im@gr and
// h = tanh([gr|last]@W_pvsd + b). Block 0 also zero-inits the loss slot
// (k3 accumulates into it atomically; stream order guarantees k1 < k3).
__global__ __launch_bounds__(256) void k1_fused(
    const int* __restrict__ nodes, const int* __restrict__ mask,
    const int* __restrict__ sli, const float* __restrict__ emb_i,
    const float* __restrict__ W_pvsd, const float* __restrict__ b_pvsd,
    const float* __restrict__ W_im,
    float* __restrict__ gnn_out, float* __restrict__ u, float* __restrict__ h,
    float* __restrict__ loss)
{
    const int b = blockIdx.x;
    const int t = threadIdx.x;
    if (b == 0 && t == 0) loss[0] = 0.f;
    __shared__ int   s_nodes[L];
    __shared__ float s_mask[L];
    __shared__ float s_part[4][D];
    __shared__ float s_gr[D], s_last[D];
    if (t < L) {
        s_nodes[t] = nodes[b * L + t];
        s_mask[t]  = (float)mask[b * L + t];
    }
    __syncthreads();
    const int d  = t & 63;
    const int l0 = t >> 6;
    float acc = 0.f;
    for (int l = l0; l < L; l += 4) {
        float val = emb_i[(size_t)s_nodes[l] * D + d];
        size_t o = ((size_t)(b * ND + 0) * L + l) * D + d;
        gnn_out[o]                   = val;
        gnn_out[o + (size_t)L * D]   = val;
        gnn_out[o + 2*(size_t)L * D] = val;
        gnn_out[o + 3*(size_t)L * D] = val;
        acc += s_mask[l] * val;
    }
    s_part[l0][d] = acc;
    __syncthreads();
    if (t < D) {
        float msum = 0.f;
        for (int l = 0; l < L; ++l) msum += s_mask[l];
        float s = s_part[0][t] + s_part[1][t] + s_part[2][t] + s_part[3][t];
        s_gr[t]   = s / msum;
        s_last[t] = emb_i[(size_t)s_nodes[sli[b]] * D + t];
    }
    __syncthreads();
    if (t < D) {
        float uu = 0.f;
        #pragma unroll
        for (int e = 0; e < D; ++e) uu += W_im[t * D + e] * s_gr[e];
        u[b * D + t] = uu;
        float pre = b_pvsd[t];
        #pragma unroll
        for (int k = 0; k < D; ++k) pre += s_gr[k]   * W_pvsd[k * D + t];
        #pragma unroll
        for (int k = 0; k < D; ++k) pre += s_last[k] * W_pvsd[(D + k) * D + t];
        h[b * D + t] = tanhf(pre);
    }
}

// K3: infomax partials per b, accumulated straight into the scalar loss.
__global__ __launch_bounds__(64) void k3_infomax(
    const float* __restrict__ u, const float* __restrict__ gnn,
    float* __restrict__ loss)
{
    const int b = blockIdx.x;
    const int t = threadIdx.x;
    __shared__ float s_up[D], s_un[D];
    const int bm1 = (b + B - 1) % B;
    s_up[t] = u[b * D + t];
    s_un[t] = u[bm1 * D + t];
    __syncthreads();
    float lsp = 0.f, lsn = 0.f;
    if (t < L) {
        const float* se = gnn + ((size_t)(b * ND) * L + t) * D;  // n=0 copy
        float sp = 0.f, sn = 0.f;
        #pragma unroll
        for (int d2 = 0; d2 < D; ++d2) {
            float vv = se[d2];
            sp += vv * s_up[d2];
            sn += vv * s_un[d2];
        }
        lsp = log_sigmoid(sp);
        lsn = log_sigmoid(-sn);
    }
    float tot = lsp + lsn;
    for (int off = 32; off > 0; off >>= 1) tot += __shfl_down(tot, off);
    if (t == 0) atomicAdd(loss, -tot / (float)(B * L));
}

// K5: P_v[b,v] = h[b] . emb_i[v]
// R7 post-mortem: streaming one 16B quad per K-step re-fetched every 64B
// line ~4x (256B-stride lanes use 1/4 of L1 sets; reuse distance = one full
// j-loop) -> FETCH 394MB, fetch-BW-bound at 141us. Fix: consume each cache
// line COMPLETELY at load time — per KB step load the thread's 4 contiguous
// quads (one 64B line, one fetch), apply to all 32 b's, then move on.
// The asm "+v" pin forces the 16 floats to materialize in VGPRs so the
// allocator cannot re-sink the loads into the j-loop (R4/R5 pathology).
// h reads are wave-uniform -> s_load (8KB/wave total, scalar-cache hot).
// Per-thread HBM fetch = exactly its 256B row; 4 b-slices of one v-tile are
// dispatch-adjacent so L2/L3 absorb the cross-slice refetch.
#define NBSPLIT 4
#define NB (B / NBSPLIT)   // 32 b per thread
__global__ __launch_bounds__(256) void k5_pv(
    const float* __restrict__ h, const float* __restrict__ emb_i,
    float* __restrict__ pv)
{
    const int bx = blockIdx.x >> 2;
    const int by = blockIdx.x & 3;
    const int v  = bx * 256 + threadIdx.x;
    const int b0 = by * NB;
    const bool active = (v < V);
    const int vc = active ? v : (V - 1);
    const float4* r4 = reinterpret_cast<const float4*>(emb_i + (size_t)vc * D);
    const float4* h4 = reinterpret_cast<const float4*>(h) + (size_t)b0 * (D / 4);

    float acc[NB];
    #pragma unroll
    for (int j = 0; j < NB; ++j) acc[j] = 0.f;

    #pragma unroll
    for (int KB = 0; KB < 4; ++KB) {
        float4 q0 = r4[4 * KB + 0];
        float4 q1 = r4[4 * KB + 1];
        float4 q2 = r4[4 * KB + 2];
        float4 q3 = r4[4 * KB + 3];
        // Pin the full 64B line in VGPRs: loads complete here, cannot be
        // sunk into (or re-issued inside) the j-loop.
        asm volatile("" : "+v"(q0.x), "+v"(q0.y), "+v"(q0.z), "+v"(q0.w),
                          "+v"(q1.x), "+v"(q1.y), "+v"(q1.z), "+v"(q1.w),
                          "+v"(q2.x), "+v"(q2.y), "+v"(q2.z), "+v"(q2.w),
                          "+v"(q3.x), "+v"(q3.y), "+v"(q3.z), "+v"(q3.w));
        #pragma unroll
        for (int j = 0; j < NB; ++j) {
            const float4* hj = h4 + (size_t)j * (D / 4) + 4 * KB;
            float4 h0 = hj[0], h1 = hj[1], h2 = hj[2], h3 = hj[3]; // s_loads
            float a = acc[j];
            a += q0.x * h0.x; a += q0.y * h0.y; a += q0.z * h0.z; a += q0.w * h0.w;
            a += q1.x * h1.x; a += q1.y * h1.y; a += q1.z * h1.z; a += q1.w * h1.w;
            a += q2.x * h2.x; a += q2.y * h2.y; a += q2.z * h2.z; a += q2.w * h2.w;
            a += q3.x * h3.x; a += q3.y * h3.y; a += q3.z * h3.z; a += q3.w * h3.w;
            acc[j] = a;
        }
    }
    if (active) {
        #pragma unroll
        for (int j = 0; j < NB; ++j)
            pv[(size_t)(b0 + j) * V + v] = acc[j];
    }
}

extern "C" void kernel_launch(void* const* d_in, const int* in_sizes, int n_in,
                              void* d_out, int out_size, void* d_ws, size_t ws_size,
                              hipStream_t stream)
{
    const int*   nodes  = (const int*)d_in[0];
    const int*   sli    = (const int*)d_in[4];
    const int*   mask   = (const int*)d_in[6];
    const float* emb_i  = (const float*)d_in[7];
    const float* W_pvsd = (const float*)d_in[13];
    const float* b_pvsd = (const float*)d_in[14];
    const float* W_im   = (const float*)d_in[15];

    float* pv   = (float*)d_out;               // B*V
    float* loss = pv + (size_t)B * V;          // 1
    float* gnn  = loss + 1;                    // B*ND*L*D

    float* ws = (float*)d_ws;
    float* u  = ws;                            // B*D
    float* h  = u + B * D;                     // B*D

    k1_fused<<<B, 256, 0, stream>>>(nodes, mask, sli, emb_i, W_pvsd, b_pvsd,
                                    W_im, gnn, u, h, loss);
    k3_infomax<<<B, 64, 0, stream>>>(u, gnn, loss);
    k5_pv<<<((V + 255) / 256) * NBSPLIT, 256, 0, stream>>>(h, emb_i, pv);
}